// Round 15
// baseline (59.479 us; speedup 1.0000x reference)
//
#include <hip/hip_runtime.h>
#include <math.h>

typedef _Float16 f16;
typedef _Float16 f16x4 __attribute__((ext_vector_type(4)));
typedef float f32x4 __attribute__((ext_vector_type(4)));

#define TPB 256
#define ROWS_PER_BLOCK 256          // 4 waves x 4 rf x 16 rows
#define CC 512                      // T-points (cols) per block

static __device__ __forceinline__ unsigned pk(f16 a, f16 b) {
    union { f16 h[2]; unsigned u; } v; v.h[0] = a; v.h[1] = b; return v.u;
}

// Encode points so that enc_row(p) . enc_col(t) = |p|^2 + |t|^2 - 2 p.t = d^2
// to ~4e-5 (hi/lo f16 split; verified r8-r14: absmax 0.0). K=16 slots.
// Also initializes gmin[NP+NT] and *out (replaces memset dispatches).
__global__ __launch_bounds__(TPB) void chamfer_encode(
    const float* __restrict__ P, int NP, const float* __restrict__ T, int NT,
    ushort* __restrict__ Prow, ushort* __restrict__ Tcol,
    unsigned* __restrict__ gminF, float* __restrict__ out)
{
    const int i = blockIdx.x * TPB + threadIdx.x;
    if (i >= NP + NT) return;
    gminF[i] = 0xFFFFFFFFu;               // gminF and gminB are contiguous
    if (i == 0) *out = 0.f;

    const float x = (i < NP) ? P[3*i]   : T[3*(i-NP)];
    const float y = (i < NP) ? P[3*i+1] : T[3*(i-NP)+1];
    const float z = (i < NP) ? P[3*i+2] : T[3*(i-NP)+2];
    const float s2 = x*x + y*y + z*z;

    const f16 xh = (f16)x,  xl = (f16)(x - (float)xh);
    const f16 yh = (f16)y,  yl = (f16)(y - (float)yh);
    const f16 zh = (f16)z,  zl = (f16)(z - (float)zh);
    const f16 sh = (f16)s2, sl = (f16)(s2 - (float)sh);
    const f16 one = (f16)1.f, zer = (f16)0.f;

    if (i < NP) {
        const float ux = -2.f*x, uy = -2.f*y, uz = -2.f*z;
        const f16 uxh = (f16)ux, uxl = (f16)(ux - (float)uxh);
        const f16 uyh = (f16)uy, uyl = (f16)(uy - (float)uyh);
        const f16 uzh = (f16)uz, uzl = (f16)(uz - (float)uzh);
        // row enc: [uxh,uxl,uxh, uyh,uyl,uyh, uzh,uzl,uzh, sh,sl, 1,1, 0,0,0]
        uint4 r0 = { pk(uxh,uxl), pk(uxh,uyh), pk(uyl,uyh), pk(uzh,uzl) };
        uint4 r1 = { pk(uzh,sh),  pk(sl,one),  pk(one,zer), pk(zer,zer) };
        *(uint4*)(Prow + (size_t)i*16)     = r0;
        *(uint4*)(Prow + (size_t)i*16 + 8) = r1;
    } else {
        const int j = i - NP;
        // col enc: [xh,xh,xl, yh,yh,yl, zh,zh,zl, 1,1, sh,sl, 0,0,0]
        uint4 c0 = { pk(xh,xh), pk(xl,yh), pk(yh,yl), pk(zh,zh) };
        uint4 c1 = { pk(zl,one), pk(one,sh), pk(sl,zer), pk(zer,zer) };
        *(uint4*)(Tcol + (size_t)j*16)     = c0;
        *(uint4*)(Tcol + (size_t)j*16 + 8) = c1;
    }
}

// Single pass, dual direction, 16x16x16 MFMA (K=16 = enc width exactly).
// Layouts (AMD matrix-core standard, 16x16x16_f16):
//   A: row=lane&15, k=4*(lane>>4)+i ; B: col=lane&15, k=4*(lane>>4)+i ;
//   D: col=lane&15, row=4*(lane>>4)+i  (same family as r8-verified 32x32).
// A/B take enc slots in the same k-order -> common-permutation invariant.
//
// LOW-PRESSURE DESIGN (r12-r14 lesson): with 32x32 shapes the live set
// (110+ floats) exceeded the ~64 arch-VGPR budget the allocator picks, so
// it homed tuples in AGPRs and paid accvgpr_read/write churn at every asm
// boundary + every fmin on AGPR-homed values (~4.5x VALU bloat, immune to
// scalar-mr / one-tuple-live variants). 16x16 shapes shrink every tuple 4x:
// peak live ~50 regs < 64 -> nothing for the allocator to put in AGPRs.
__global__ __launch_bounds__(TPB) void chamfer_mfma(
    const ushort* __restrict__ Prow, int NP,
    const ushort* __restrict__ Tcol, int NT,
    unsigned* __restrict__ gminF, unsigned* __restrict__ gminB)
{
    const int rowbase = blockIdx.x * ROWS_PER_BLOCK;
    const int col0 = blockIdx.y * CC;
    if (rowbase >= NP || col0 >= NT) return;

    __shared__ alignas(8) ushort Blds[4 * CC * 4];   // 16 KB [kq][col][4]
    __shared__ float colw[4][CC];                    // 8 KB [wave][col]

    const int tid = threadIdx.x;
    for (int t = tid; t < CC; t += TPB) {   // stage B cols, split by k-quad
        const int c = min(col0 + t, NT - 1);
        const uint2* s = (const uint2*)(Tcol + (size_t)c * 16);
        *(uint2*)(&Blds[(0 * CC + t) * 4]) = s[0];
        *(uint2*)(&Blds[(1 * CC + t) * 4]) = s[1];
        *(uint2*)(&Blds[(2 * CC + t) * 4]) = s[2];
        *(uint2*)(&Blds[(3 * CC + t) * 4]) = s[3];
    }
    __syncthreads();

    const int l = tid & 63, w = tid >> 6;
    const int kq = l >> 4;     // k-quad this lane feeds (k = kq*4..kq*4+3)
    const int c16 = l & 15;    // col (B/D) / row (A) index within 16-tile

    // A fragments from global, once (L2-resident); rf = 4 row-frags of 16
    f16x4 af0, af1, af2, af3;
    {
        const int r0 = min(rowbase + 0 * 16 + c16, NP - 1);
        const int r1 = min(rowbase + 1 * 16 + c16 + w * 64, NP - 1); // placeholder, fixed below
        (void)r1;
        const int base = rowbase + w * 64;
        af0 = *(const f16x4*)(Prow + (size_t)min(base + 0 * 16 + c16, NP - 1) * 16 + kq * 4);
        af1 = *(const f16x4*)(Prow + (size_t)min(base + 1 * 16 + c16, NP - 1) * 16 + kq * 4);
        af2 = *(const f16x4*)(Prow + (size_t)min(base + 2 * 16 + c16, NP - 1) * 16 + kq * 4);
        af3 = *(const f16x4*)(Prow + (size_t)min(base + 3 * 16 + c16, NP - 1) * 16 + kq * 4);
    }

    const f32x4 z = {0.f, 0.f, 0.f, 0.f};
    float mr[16];
#pragma unroll
    for (int r = 0; r < 16; r++) mr[r] = 3.4e38f;

    const ushort* Bw = Blds + kq * CC * 4;
#pragma unroll 1
    for (int cb = 0; cb < CC / 16; ++cb) {
        const f16x4 bf = *(const f16x4*)(Bw + (cb * 16 + c16) * 4);

        f32x4 d0, d1;
        asm volatile(
            "v_mfma_f32_16x16x16_f16 %0, %2, %4, %5\n\t"
            "v_mfma_f32_16x16x16_f16 %1, %3, %4, %5\n\t"
            "s_nop 7\n\ts_nop 7"
            : "=&v"(d0), "=&v"(d1)
            : "v"(af0), "v"(af1), "v"(bf), "v"(z));
        mr[0]  = fminf(mr[0],  d0[0]); mr[1]  = fminf(mr[1],  d0[1]);
        mr[2]  = fminf(mr[2],  d0[2]); mr[3]  = fminf(mr[3],  d0[3]);
        mr[4]  = fminf(mr[4],  d1[0]); mr[5]  = fminf(mr[5],  d1[1]);
        mr[6]  = fminf(mr[6],  d1[2]); mr[7]  = fminf(mr[7],  d1[3]);
        float cm = fminf(fminf(fminf(d0[0], d0[1]), fminf(d0[2], d0[3])),
                         fminf(fminf(d1[0], d1[1]), fminf(d1[2], d1[3])));

        asm volatile(
            "v_mfma_f32_16x16x16_f16 %0, %2, %4, %5\n\t"
            "v_mfma_f32_16x16x16_f16 %1, %3, %4, %5\n\t"
            "s_nop 7\n\ts_nop 7"
            : "=&v"(d0), "=&v"(d1)
            : "v"(af2), "v"(af3), "v"(bf), "v"(z));
        mr[8]  = fminf(mr[8],  d0[0]); mr[9]  = fminf(mr[9],  d0[1]);
        mr[10] = fminf(mr[10], d0[2]); mr[11] = fminf(mr[11], d0[3]);
        mr[12] = fminf(mr[12], d1[0]); mr[13] = fminf(mr[13], d1[1]);
        mr[14] = fminf(mr[14], d1[2]); mr[15] = fminf(mr[15], d1[3]);
        cm = fminf(cm, fminf(fminf(fminf(d0[0], d0[1]), fminf(d0[2], d0[3])),
                             fminf(fminf(d1[0], d1[1]), fminf(d1[2], d1[3]))));

        // fold the 4 kq row-groups (lanes l^16, l^32): cols live in lane&15
        cm = fminf(cm, __shfl_xor(cm, 16));
        cm = fminf(cm, __shfl_xor(cm, 32));
        if (l < 16) colw[w][cb * 16 + l] = fmaxf(cm, 0.f);
    }

    // forward: reduce row-min over the 16 cols, one atomicMin per row
#pragma unroll
    for (int rf = 0; rf < 4; rf++) {
#pragma unroll
        for (int i = 0; i < 4; i++) {
            float v = mr[rf * 4 + i];
            v = fminf(v, __shfl_xor(v, 1));
            v = fminf(v, __shfl_xor(v, 2));
            v = fminf(v, __shfl_xor(v, 4));
            v = fminf(v, __shfl_xor(v, 8));
            if (c16 == 0) {
                const int row = rowbase + w * 64 + rf * 16 + kq * 4 + i;
                if (row < NP)
                    atomicMin(&gminF[row], __float_as_uint(fmaxf(v, 0.f)));
            }
        }
    }

    // backward: fold the 4 per-wave planes, one global atomic per col
    __syncthreads();
    for (int t = tid; t < CC; t += TPB) {
        const int c = col0 + t;
        if (c >= NT) break;
        const float v = fminf(fminf(colw[0][t], colw[1][t]),
                              fminf(colw[2][t], colw[3][t]));
        atomicMin(&gminB[c], __float_as_uint(v));
    }
}

// gmin bits -> sqrt -> scaled sum into *out.
__global__ __launch_bounds__(TPB) void chamfer_final(
    const unsigned* __restrict__ gminF, int NP,
    const unsigned* __restrict__ gminB, int NT,
    float scaleF, float scaleB, float* __restrict__ out)
{
    const int gid = blockIdx.x * TPB + threadIdx.x;
    float val = 0.f;
    if (gid < NP) {
        val = sqrtf(fmaxf(__uint_as_float(gminF[gid]), 0.f)) * scaleF;
    } else if (gid < NP + NT) {
        val = sqrtf(fmaxf(__uint_as_float(gminB[gid - NP]), 0.f)) * scaleB;
    }
#pragma unroll
    for (int off = 32; off > 0; off >>= 1) val += __shfl_down(val, off);
    __shared__ float red[TPB / 64];
    const int lane = threadIdx.x & 63;
    const int w = threadIdx.x >> 6;
    if (lane == 0) red[w] = val;
    __syncthreads();
    if (threadIdx.x == 0) {
        float s = 0.f;
#pragma unroll
        for (int i = 0; i < TPB / 64; i++) s += red[i];
        atomicAdd(out, s);
    }
}

extern "C" void kernel_launch(void* const* d_in, const int* in_sizes, int n_in,
                              void* d_out, int out_size, void* d_ws, size_t ws_size,
                              hipStream_t stream) {
    const float* P = (const float*)d_in[0];
    const float* T = (const float*)d_in[1];
    const int NP = in_sizes[0] / 3;
    const int NT = in_sizes[1] / 3;
    float* out = (float*)d_out;

    unsigned* gminF = (unsigned*)d_ws;
    unsigned* gminB = gminF + NP;
    ushort* Prow = (ushort*)(gminB + NT);
    ushort* Tcol = Prow + (size_t)NP * 16;
    // ws usage: (NP+NT)*4 + (NP+NT)*32 bytes ~= 1.2 MB

    const int eblocks = (NP + NT + TPB - 1) / TPB;
    chamfer_encode<<<eblocks, TPB, 0, stream>>>(P, NP, T, NT, Prow, Tcol, gminF, out);

    dim3 grid((NP + ROWS_PER_BLOCK - 1) / ROWS_PER_BLOCK,
              (NT + CC - 1) / CC, 1);
    chamfer_mfma<<<grid, TPB, 0, stream>>>(Prow, NP, Tcol, NT, gminF, gminB);

    const int fblocks = (NP + NT + TPB - 1) / TPB;
    chamfer_final<<<fblocks, TPB, 0, stream>>>(gminF, NP, gminB, NT,
                                               1.0f / (float)NP, 1.0f / (float)NT, out);
}

// Round 16
// 59.161 us; speedup vs baseline: 1.0054x; 1.0054x over previous
//
#include <hip/hip_runtime.h>
#include <math.h>

typedef _Float16 f16;
typedef _Float16 f16x4 __attribute__((ext_vector_type(4)));
typedef float f32x4 __attribute__((ext_vector_type(4)));

#define TPB 256
#define ROWS_PER_BLOCK 256          // 4 waves x 4 rf x 16 rows
#define CC 512                      // T-points (cols) per block

static __device__ __forceinline__ unsigned pk(f16 a, f16 b) {
    union { f16 h[2]; unsigned u; } v; v.h[0] = a; v.h[1] = b; return v.u;
}

// Encode points so that enc_row(p) . enc_col(t) = |p|^2 + |t|^2 - 2 p.t = d^2
// to ~4e-5 (hi/lo f16 split; verified r8-r14: absmax 0.0). K=16 slots.
// Also initializes gmin[NP+NT] and *out (replaces memset dispatches).
__global__ __launch_bounds__(TPB) void chamfer_encode(
    const float* __restrict__ P, int NP, const float* __restrict__ T, int NT,
    ushort* __restrict__ Prow, ushort* __restrict__ Tcol,
    unsigned* __restrict__ gminF, float* __restrict__ out)
{
    const int i = blockIdx.x * TPB + threadIdx.x;
    if (i >= NP + NT) return;
    gminF[i] = 0xFFFFFFFFu;               // gminF and gminB are contiguous
    if (i == 0) *out = 0.f;

    const float x = (i < NP) ? P[3*i]   : T[3*(i-NP)];
    const float y = (i < NP) ? P[3*i+1] : T[3*(i-NP)+1];
    const float z = (i < NP) ? P[3*i+2] : T[3*(i-NP)+2];
    const float s2 = x*x + y*y + z*z;

    const f16 xh = (f16)x,  xl = (f16)(x - (float)xh);
    const f16 yh = (f16)y,  yl = (f16)(y - (float)yh);
    const f16 zh = (f16)z,  zl = (f16)(z - (float)zh);
    const f16 sh = (f16)s2, sl = (f16)(s2 - (float)sh);
    const f16 one = (f16)1.f, zer = (f16)0.f;

    if (i < NP) {
        const float ux = -2.f*x, uy = -2.f*y, uz = -2.f*z;
        const f16 uxh = (f16)ux, uxl = (f16)(ux - (float)uxh);
        const f16 uyh = (f16)uy, uyl = (f16)(uy - (float)uyh);
        const f16 uzh = (f16)uz, uzl = (f16)(uz - (float)uzh);
        // row enc: [uxh,uxl,uxh, uyh,uyl,uyh, uzh,uzl,uzh, sh,sl, 1,1, 0,0,0]
        uint4 r0 = { pk(uxh,uxl), pk(uxh,uyh), pk(uyl,uyh), pk(uzh,uzl) };
        uint4 r1 = { pk(uzh,sh),  pk(sl,one),  pk(one,zer), pk(zer,zer) };
        *(uint4*)(Prow + (size_t)i*16)     = r0;
        *(uint4*)(Prow + (size_t)i*16 + 8) = r1;
    } else {
        const int j = i - NP;
        // col enc: [xh,xh,xl, yh,yh,yl, zh,zh,zl, 1,1, sh,sl, 0,0,0]
        uint4 c0 = { pk(xh,xh), pk(xl,yh), pk(yh,yl), pk(zh,zh) };
        uint4 c1 = { pk(zl,one), pk(one,sh), pk(sl,zer), pk(zer,zer) };
        *(uint4*)(Tcol + (size_t)j*16)     = c0;
        *(uint4*)(Tcol + (size_t)j*16 + 8) = c1;
    }
}

// Single pass, dual direction, 16x16x16 MFMA (K=16 = enc width exactly).
// Layouts (AMD matrix-core standard, 16x16x16_f16):
//   A: row=lane&15, k=4*(lane>>4)+i ; B: col=lane&15, k=4*(lane>>4)+i ;
//   D: col=lane&15, row=4*(lane>>4)+i  (same family as r8-verified 32x32).
// A/B take enc slots in the same k-order -> common-permutation invariant.
//
// LOW-PRESSURE DESIGN (r12-r14 lesson): with 32x32 shapes the live set
// (110+ floats) exceeded the ~64 arch-VGPR budget the allocator picks, so
// it homed tuples in AGPRs and paid accvgpr_read/write churn at every asm
// boundary + every fmin on AGPR-homed values (~4.5x VALU bloat, immune to
// scalar-mr / one-tuple-live variants). 16x16 shapes shrink every tuple 4x:
// peak live ~50 regs < 64 -> nothing for the allocator to put in AGPRs.
__global__ __launch_bounds__(TPB) void chamfer_mfma(
    const ushort* __restrict__ Prow, int NP,
    const ushort* __restrict__ Tcol, int NT,
    unsigned* __restrict__ gminF, unsigned* __restrict__ gminB)
{
    const int rowbase = blockIdx.x * ROWS_PER_BLOCK;
    const int col0 = blockIdx.y * CC;
    if (rowbase >= NP || col0 >= NT) return;

    __shared__ alignas(8) ushort Blds[4 * CC * 4];   // 16 KB [kq][col][4]
    __shared__ float colw[4][CC];                    // 8 KB [wave][col]

    const int tid = threadIdx.x;
    for (int t = tid; t < CC; t += TPB) {   // stage B cols, split by k-quad
        const int c = min(col0 + t, NT - 1);
        const uint2* s = (const uint2*)(Tcol + (size_t)c * 16);
        *(uint2*)(&Blds[(0 * CC + t) * 4]) = s[0];
        *(uint2*)(&Blds[(1 * CC + t) * 4]) = s[1];
        *(uint2*)(&Blds[(2 * CC + t) * 4]) = s[2];
        *(uint2*)(&Blds[(3 * CC + t) * 4]) = s[3];
    }
    __syncthreads();

    const int l = tid & 63, w = tid >> 6;
    const int kq = l >> 4;     // k-quad this lane feeds (k = kq*4..kq*4+3)
    const int c16 = l & 15;    // col (B/D) / row (A) index within 16-tile

    // A fragments from global, once (L2-resident); rf = 4 row-frags of 16
    f16x4 af0, af1, af2, af3;
    {
        const int r0 = min(rowbase + 0 * 16 + c16, NP - 1);
        const int r1 = min(rowbase + 1 * 16 + c16 + w * 64, NP - 1); // placeholder, fixed below
        (void)r1;
        const int base = rowbase + w * 64;
        af0 = *(const f16x4*)(Prow + (size_t)min(base + 0 * 16 + c16, NP - 1) * 16 + kq * 4);
        af1 = *(const f16x4*)(Prow + (size_t)min(base + 1 * 16 + c16, NP - 1) * 16 + kq * 4);
        af2 = *(const f16x4*)(Prow + (size_t)min(base + 2 * 16 + c16, NP - 1) * 16 + kq * 4);
        af3 = *(const f16x4*)(Prow + (size_t)min(base + 3 * 16 + c16, NP - 1) * 16 + kq * 4);
    }

    const f32x4 z = {0.f, 0.f, 0.f, 0.f};
    float mr[16];
#pragma unroll
    for (int r = 0; r < 16; r++) mr[r] = 3.4e38f;

    const ushort* Bw = Blds + kq * CC * 4;
#pragma unroll 1
    for (int cb = 0; cb < CC / 16; ++cb) {
        const f16x4 bf = *(const f16x4*)(Bw + (cb * 16 + c16) * 4);

        f32x4 d0, d1;
        asm volatile(
            "v_mfma_f32_16x16x16_f16 %0, %2, %4, %5\n\t"
            "v_mfma_f32_16x16x16_f16 %1, %3, %4, %5\n\t"
            "s_nop 7\n\ts_nop 7"
            : "=&v"(d0), "=&v"(d1)
            : "v"(af0), "v"(af1), "v"(bf), "v"(z));
        mr[0]  = fminf(mr[0],  d0[0]); mr[1]  = fminf(mr[1],  d0[1]);
        mr[2]  = fminf(mr[2],  d0[2]); mr[3]  = fminf(mr[3],  d0[3]);
        mr[4]  = fminf(mr[4],  d1[0]); mr[5]  = fminf(mr[5],  d1[1]);
        mr[6]  = fminf(mr[6],  d1[2]); mr[7]  = fminf(mr[7],  d1[3]);
        float cm = fminf(fminf(fminf(d0[0], d0[1]), fminf(d0[2], d0[3])),
                         fminf(fminf(d1[0], d1[1]), fminf(d1[2], d1[3])));

        asm volatile(
            "v_mfma_f32_16x16x16_f16 %0, %2, %4, %5\n\t"
            "v_mfma_f32_16x16x16_f16 %1, %3, %4, %5\n\t"
            "s_nop 7\n\ts_nop 7"
            : "=&v"(d0), "=&v"(d1)
            : "v"(af2), "v"(af3), "v"(bf), "v"(z));
        mr[8]  = fminf(mr[8],  d0[0]); mr[9]  = fminf(mr[9],  d0[1]);
        mr[10] = fminf(mr[10], d0[2]); mr[11] = fminf(mr[11], d0[3]);
        mr[12] = fminf(mr[12], d1[0]); mr[13] = fminf(mr[13], d1[1]);
        mr[14] = fminf(mr[14], d1[2]); mr[15] = fminf(mr[15], d1[3]);
        cm = fminf(cm, fminf(fminf(fminf(d0[0], d0[1]), fminf(d0[2], d0[3])),
                             fminf(fminf(d1[0], d1[1]), fminf(d1[2], d1[3]))));

        // fold the 4 kq row-groups (lanes l^16, l^32): cols live in lane&15
        cm = fminf(cm, __shfl_xor(cm, 16));
        cm = fminf(cm, __shfl_xor(cm, 32));
        if (l < 16) colw[w][cb * 16 + l] = fmaxf(cm, 0.f);
    }

    // forward: reduce row-min over the 16 cols, one atomicMin per row
#pragma unroll
    for (int rf = 0; rf < 4; rf++) {
#pragma unroll
        for (int i = 0; i < 4; i++) {
            float v = mr[rf * 4 + i];
            v = fminf(v, __shfl_xor(v, 1));
            v = fminf(v, __shfl_xor(v, 2));
            v = fminf(v, __shfl_xor(v, 4));
            v = fminf(v, __shfl_xor(v, 8));
            if (c16 == 0) {
                const int row = rowbase + w * 64 + rf * 16 + kq * 4 + i;
                if (row < NP)
                    atomicMin(&gminF[row], __float_as_uint(fmaxf(v, 0.f)));
            }
        }
    }

    // backward: fold the 4 per-wave planes, one global atomic per col
    __syncthreads();
    for (int t = tid; t < CC; t += TPB) {
        const int c = col0 + t;
        if (c >= NT) break;
        const float v = fminf(fminf(colw[0][t], colw[1][t]),
                              fminf(colw[2][t], colw[3][t]));
        atomicMin(&gminB[c], __float_as_uint(v));
    }
}

// gmin bits -> sqrt -> scaled sum into *out.
__global__ __launch_bounds__(TPB) void chamfer_final(
    const unsigned* __restrict__ gminF, int NP,
    const unsigned* __restrict__ gminB, int NT,
    float scaleF, float scaleB, float* __restrict__ out)
{
    const int gid = blockIdx.x * TPB + threadIdx.x;
    float val = 0.f;
    if (gid < NP) {
        val = sqrtf(fmaxf(__uint_as_float(gminF[gid]), 0.f)) * scaleF;
    } else if (gid < NP + NT) {
        val = sqrtf(fmaxf(__uint_as_float(gminB[gid - NP]), 0.f)) * scaleB;
    }
#pragma unroll
    for (int off = 32; off > 0; off >>= 1) val += __shfl_down(val, off);
    __shared__ float red[TPB / 64];
    const int lane = threadIdx.x & 63;
    const int w = threadIdx.x >> 6;
    if (lane == 0) red[w] = val;
    __syncthreads();
    if (threadIdx.x == 0) {
        float s = 0.f;
#pragma unroll
        for (int i = 0; i < TPB / 64; i++) s += red[i];
        atomicAdd(out, s);
    }
}

extern "C" void kernel_launch(void* const* d_in, const int* in_sizes, int n_in,
                              void* d_out, int out_size, void* d_ws, size_t ws_size,
                              hipStream_t stream) {
    const float* P = (const float*)d_in[0];
    const float* T = (const float*)d_in[1];
    const int NP = in_sizes[0] / 3;
    const int NT = in_sizes[1] / 3;
    float* out = (float*)d_out;

    unsigned* gminF = (unsigned*)d_ws;
    unsigned* gminB = gminF + NP;
    ushort* Prow = (ushort*)(gminB + NT);
    ushort* Tcol = Prow + (size_t)NP * 16;
    // ws usage: (NP+NT)*4 + (NP+NT)*32 bytes ~= 1.2 MB

    const int eblocks = (NP + NT + TPB - 1) / TPB;
    chamfer_encode<<<eblocks, TPB, 0, stream>>>(P, NP, T, NT, Prow, Tcol, gminF, out);

    dim3 grid((NP + ROWS_PER_BLOCK - 1) / ROWS_PER_BLOCK,
              (NT + CC - 1) / CC, 1);
    chamfer_mfma<<<grid, TPB, 0, stream>>>(Prow, NP, Tcol, NT, gminF, gminB);

    const int fblocks = (NP + NT + TPB - 1) / TPB;
    chamfer_final<<<fblocks, TPB, 0, stream>>>(gminF, NP, gminB, NT,
                                               1.0f / (float)NP, 1.0f / (float)NT, out);
}